// Round 12
// baseline (179.240 us; speedup 1.0000x reference)
//
#include <hip/hip_runtime.h>

#define NBH 32      // B*H
#define LL  2048
#define DD  64
#define BQ  64      // q rows per block
#define BK  64      // k tile
#define NT  32      // LL/BK
#define NG  8       // k-tile groups (4 tiles each) in loop2
#define CSHIFT 120.0f

typedef _Float16 f16;
typedef _Float16 f16x4 __attribute__((ext_vector_type(4)));
typedef _Float16 f16x8 __attribute__((ext_vector_type(8)));
typedef _Float16 f16x8a __attribute__((ext_vector_type(8), may_alias));
typedef _Float16 f16x4a __attribute__((ext_vector_type(4), may_alias));
typedef float f32x4 __attribute__((ext_vector_type(4)));

__device__ __forceinline__ float elu1(float x) { return x > 0.f ? x + 1.f : __expf(x); }

// prep: featurize K, transpose V, and emit BOTH in fragment-major layout:
// 1KB block per (kt, n, ka); lane l's 16B at blockbase + l*16 equals exactly
// the bytes the old swizzled-LDS fragment read returned:
//   K block: K[kt*64 + 16n + (l&15)][32ka + 8*(l>>4) .. +7]   (elu1, f16)
//   V block: V^T[16n + (l&15)][kt*64 + 32ka + 8*(l>>4) .. +7] (f16)
__global__ void prep(const float* __restrict__ K, const float* __restrict__ V,
                     f16* __restrict__ Kfg, f16* __restrict__ Vfg) {
  __shared__ f16 Ltk[64][72];   // featurized K rows [k][d]
  __shared__ f16 Ltv[64][72];   // V rows [k][d]
  __shared__ f16 VtL[64][72];   // V transposed [d][k]
  const int bh = blockIdx.y, kt = blockIdx.x, r0 = kt * 64;
  const int t = threadIdx.x;
#pragma unroll
  for (int it = 0; it < 4; ++it) {
    int idx = t + 256 * it;
    int r = idx >> 4, d0 = (idx & 15) * 4;
    float4 kv = *(const float4*)(K + (size_t)(bh * LL + r0 + r) * DD + d0);
    f16x4 kh = { (f16)elu1(kv.x), (f16)elu1(kv.y), (f16)elu1(kv.z), (f16)elu1(kv.w) };
    *(f16x4a*)&Ltk[r][d0] = kh;
    float4 vv = *(const float4*)(V + (size_t)(bh * LL + r0 + r) * DD + d0);
    f16x4 vh = { (f16)vv.x, (f16)vv.y, (f16)vv.z, (f16)vv.w };
    *(f16x4a*)&Ltv[r][d0] = vh;
  }
  __syncthreads();
  const int w = t >> 6, l = t & 63;
#pragma unroll
  for (int it = 0; it < 2; ++it) {
    int s = w + 4 * it;
    f16x8 o;
#pragma unroll
    for (int j = 0; j < 8; ++j) o[j] = Ltv[8 * s + j][l];
    *(f16x8a*)&VtL[l][8 * s] = o;
  }
  __syncthreads();
  const int c = l & 15, g = l >> 4;
  char* kdst = (char*)Kfg + ((size_t)bh << 18) + ((size_t)kt << 13);
  char* vdst = (char*)Vfg + ((size_t)bh << 18) + ((size_t)kt << 13);
#pragma unroll
  for (int p = 0; p < 2; ++p) {
    int fb = w + 4 * p;                 // 0..7 = n*2+ka
    int n = fb >> 1, ka = fb & 1;
    f16x8 kf = *(const f16x8a*)&Ltk[16 * n + c][32 * ka + 8 * g];
    *(f16x8*)(kdst + (fb << 10) + l * 16) = kf;
    f16x8 vf = *(const f16x8a*)&VtL[16 * n + c][32 * ka + 8 * g];
    *(f16x8*)(vdst + (fb << 10) + l * 16) = vf;
  }
}

// R11 structure (zero barriers, fragment-major direct-global K/V reads,
// wave-private Pf) + 4-tile store batching: Pf holds a [64q][256k] fp16 group
// so each attn store instruction writes ONE FULL 1KB-contiguous row slice
// (64 lanes x 16B = 256 consecutive floats, 8 full 128B lines) instead of
// 4 scattered 256B segments -> better HBM channel locality for the nt stream.
//   QK: acc = mfma(Kfrag, Qfrag) -> lane holds s[k=16n+4g+i][q=16w+c]
//   PV: ctx = mfma(Vfrag, Pfrag) -> lane holds ctx[d=16n+4g+i][q=16w+c]
__launch_bounds__(256, 3)
__global__ void attn_fused(const float* __restrict__ Q, const f16* __restrict__ Kfg,
                           const f16* __restrict__ Vfg,
                           float* __restrict__ ctx_out, float* __restrict__ attn_out) {
  __shared__ f16 Pf[BQ * BK * 4];  // 32 KB; [q][sub(4)][128B], per-sub 16B-slot swizzle
  const int bh = blockIdx.y, q0 = blockIdx.x * BQ;
  const int t = threadIdx.x, w = t >> 6, l = t & 63, g = l >> 4, c = l & 15;
  const char* Kh = (const char*)Kfg + ((size_t)bh << 18);
  const char* Vh = (const char*)Vfg + ((size_t)bh << 18);
  float* __restrict__ attn_h = attn_out + (size_t)bh * LL * LL;

  // Q fragments from global, featurized in-reg. Lane holds Q[16w+c][32ka+8g+j].
  const int qrow = q0 + 16 * w + c;
  f16x8 qf[2];
#pragma unroll
  for (int ka = 0; ka < 2; ++ka) {
    const float* qp = Q + (size_t)(bh * LL + qrow) * DD + 32 * ka + 8 * g;
    float4 a = *(const float4*)qp;
    float4 b = *(const float4*)(qp + 4);
    f16x8 h = { (f16)elu1(a.x), (f16)elu1(a.y), (f16)elu1(a.z), (f16)elu1(a.w),
                (f16)elu1(b.x), (f16)elu1(b.y), (f16)elu1(b.z), (f16)elu1(b.w) };
    qf[ka] = h;
  }

  // ================= loop 1: rowsums (free-running) =================
  float rs = 0.f;
#pragma unroll 2
  for (int kt = 0; kt < NT; ++kt) {
    const char* kb = Kh + ((size_t)kt << 13);
#pragma unroll
    for (int n = 0; n < 4; ++n) {
      f32x4 acc = {0.f, 0.f, 0.f, 0.f};
#pragma unroll
      for (int ka = 0; ka < 2; ++ka) {
        f16x8 kfr = *(const f16x8a*)(kb + ((n * 2 + ka) << 10) + l * 16);
        acc = __builtin_amdgcn_mfma_f32_16x16x32_f16(kfr, qf[ka], acc, 0, 0, 0);
      }
#pragma unroll
      for (int i = 0; i < 4; ++i) rs += __expf(acc[i] - CSHIFT);
    }
  }
  rs += __shfl_xor(rs, 16);
  rs += __shfl_xor(rs, 32);
  const float inv = 1.0f / rs;

  // ================= loop 2: recompute + attn + PV =================
  f32x4 ctx[4];
#pragma unroll
  for (int n = 0; n < 4; ++n) ctx[n] = (f32x4){0.f, 0.f, 0.f, 0.f};

  for (int ktg = 0; ktg < NG; ++ktg) {
#pragma unroll
    for (int kts = 0; kts < 4; ++kts) {
      const int kt = ktg * 4 + kts;
      const char* kb = Kh + ((size_t)kt << 13);
      const char* vb = Vh + ((size_t)kt << 13);
#pragma unroll
      for (int n = 0; n < 4; ++n) {
        f32x4 acc = {0.f, 0.f, 0.f, 0.f};
#pragma unroll
        for (int ka = 0; ka < 2; ++ka) {
          f16x8 kfr = *(const f16x8a*)(kb + ((n * 2 + ka) << 10) + l * 16);
          acc = __builtin_amdgcn_mfma_f32_16x16x32_f16(kfr, qf[ka], acc, 0, 0, 0);
        }
        f32x4 p;
#pragma unroll
        for (int i = 0; i < 4; ++i) p[i] = __expf(acc[i] - CSHIFT) * inv;  // normalized
        f16x4 ph = { (f16)p[0], (f16)p[1], (f16)p[2], (f16)p[3] };
        int slot = (2 * n + (g >> 1)) ^ (c & 7);
        *(f16x4a*)((char*)Pf + (16 * w + c) * 512 + kts * 128 + slot * 16 + (g & 1) * 8) = ph;
      }
      // PV: B-frag from Pf (wave-private rows), A-frag from fragment-major Vfg.
#pragma unroll
      for (int ka = 0; ka < 2; ++ka) {
        f16x8 pf = (f16x8)(*(const f16x8a*)((const char*)Pf + (16 * w + c) * 512 + kts * 128 + (((4 * ka + g) ^ (c & 7)) << 4)));
#pragma unroll
        for (int n = 0; n < 4; ++n) {
          f16x8 vfr = *(const f16x8a*)(vb + ((n * 2 + ka) << 10) + l * 16);
          ctx[n] = __builtin_amdgcn_mfma_f32_16x16x32_f16(vfr, pf, ctx[n], 0, 0, 0);
        }
      }
    }
    // store phase: one 1KB-contiguous nt store per attn row slice (16 rows/wave).
    // Lane l covers k = 256*ktg + l*4 ..+3: sub = l>>4, u = l&15, inverse swizzle.
    float* gbase = attn_h + (size_t)q0 * LL + ktg * 256;
#pragma unroll
    for (int rr = 0; rr < 16; ++rr) {
      int r_loc = 16 * w + rr;
      int u = l & 15;
      int phys = (l >> 4) * 128 + (((u >> 1) ^ (r_loc & 7)) << 4) + (u & 1) * 8;
      f16x4 hv = *(const f16x4a*)((const char*)Pf + r_loc * 512 + phys);
      f32x4 sv = { (float)hv[0], (float)hv[1], (float)hv[2], (float)hv[3] };
      __builtin_nontemporal_store(sv, (f32x4*)(gbase + (size_t)r_loc * LL + 4 * l));
    }
  }

#pragma unroll
  for (int n = 0; n < 4; ++n)
    *(f32x4*)(ctx_out + (size_t)(bh * LL + qrow) * DD + n * 16 + 4 * g) = ctx[n];
}

extern "C" void kernel_launch(void* const* d_in, const int* in_sizes, int n_in,
                              void* d_out, int out_size, void* d_ws, size_t ws_size,
                              hipStream_t stream) {
  const float* Q = (const float*)d_in[0];
  const float* K = (const float*)d_in[1];
  const float* V = (const float*)d_in[2];

  float* ctx_out  = (float*)d_out;                      // [32][2048][64]
  float* attn_out = ctx_out + (size_t)NBH * LL * DD;    // [32][2048][2048]

  f16* Kfg = (f16*)d_ws;                                // fragment-major K, 8 MB
  f16* Vfg = Kfg + (size_t)NBH * LL * DD;               // fragment-major V^T, 8 MB

  hipLaunchKernelGGL(prep, dim3(LL / 64, NBH), dim3(256), 0, stream, K, V, Kfg, Vfg);
  hipLaunchKernelGGL(attn_fused, dim3(LL / BQ, NBH), dim3(256), 0, stream,
                     Q, Kfg, Vfg, ctx_out, attn_out);
}